// Round 13
// baseline (23.861 us; speedup 1.0000x reference)
//
#include <hip/hip_runtime.h>
#include <cstdint>
#include <cstddef>

#define MAXG 128

// ---------------- compile-time: reproduce numpy legacy RandomState(42) ----------------
namespace ct {

struct MT19937 {
  uint32_t mt[624] = {};
  int mti = 0;
  constexpr void seed(uint32_t s) {
    mt[0] = s;
    for (int i = 1; i < 624; i++)
      mt[i] = 1812433253u * (mt[i-1] ^ (mt[i-1] >> 30)) + (uint32_t)i;
    mti = 624;
  }
  constexpr uint32_t next() {
    if (mti >= 624) {
      for (int i = 0; i < 624; i++) {
        uint32_t y = (mt[i] & 0x80000000u) | (mt[(i+1) % 624] & 0x7fffffffu);
        mt[i] = mt[(i+397) % 624] ^ (y >> 1) ^ ((y & 1u) ? 2567483615u : 0u);
      }
      mti = 0;
    }
    uint32_t y = mt[mti++];
    y ^= y >> 11; y ^= (y << 7) & 2636928640u; y ^= (y << 15) & 4022730752u; y ^= y >> 18;
    return y;
  }
  constexpr double rdouble() {
    uint32_t a = next() >> 5, b = next() >> 6;
    return ((double)a * 67108864.0 + (double)b) / 9007199254740992.0;
  }
  constexpr uint32_t masked32(uint32_t rng, uint32_t mask) {
    uint32_t v = next() & mask;
    while (v > rng) v = next() & mask;
    return v;
  }
  constexpr uint32_t interval(uint32_t mx) {
    if (!mx) return 0;
    uint32_t mask = mx;
    mask |= mask >> 1; mask |= mask >> 2; mask |= mask >> 4; mask |= mask >> 8; mask |= mask >> 16;
    uint32_t v = next() & mask;
    while (v > mx) v = next() & mask;
    return v;
  }
};

struct CG { int n = 0; int code[MAXG] = {}; };

constexpr CG build_gates_ct() {
  CG gl{};
  MT19937 rng{};
  rng.seed(42);
  for (int l = 0; l < 4; l++) {
    int i = 0;
    while (i < 8) {
      if (rng.rdouble() > 0.3) {
        int g = (int)rng.masked32(2, 3);
        int w = (int)rng.masked32(3, 3);
        int widx = l * 8 + i;
        if (gl.n < MAXG) gl.code[gl.n++] = g | ((8 >> w) << 2) | (widx << 6);
        i++;
      } else {
        int perm[4] = {0, 1, 2, 3};
        for (int ii = 3; ii >= 1; ii--) {
          int j = (int)rng.interval((uint32_t)ii);
          int tmp = perm[ii]; perm[ii] = perm[j]; perm[j] = tmp;
        }
        int cw = perm[0], tw = perm[1];
        if (gl.n < MAXG) gl.code[gl.n++] = 3 | ((8 >> cw) << 2) | ((8 >> tw) << 6);
      }
    }
  }
  return gl;
}

constexpr CG GL = build_gates_ct();

} // namespace ct

typedef __attribute__((ext_vector_type(8))) short short8;   // 8 bf16 (4 VGPR) MFMA frag
typedef __attribute__((ext_vector_type(4))) float f32x4;    // 16x16 accumulator

// Native trig (validated R7/R11: absmax unchanged). Revolutions; |rev| < 0.5.
__device__ __forceinline__ void half_sincos(float a, float& s, float& c) {
  const float r = a * 0.07957747154594767f;   // a * 0.5 / (2*pi)
  s = __builtin_amdgcn_sinf(r);
  c = __builtin_amdgcn_cosf(r);
}

__device__ __forceinline__ float hi_part(float a) {
  return __uint_as_float(__float_as_uint(a) & 0xffff0000u);
}
__device__ __forceinline__ unsigned pack_hi(float a, float b) {   // low short = a's bf16
  return (__float_as_uint(a) >> 16) | (__float_as_uint(b) & 0xffff0000u);
}
__device__ __forceinline__ short8 pack8(float v0, float v1, float v2, float v3,
                                        float v4, float v5, float v6, float v7) {
  union { unsigned u[4]; short8 s; } r;
  r.u[0] = pack_hi(v0, v1); r.u[1] = pack_hi(v2, v3);
  r.u[2] = pack_hi(v4, v5); r.u[3] = pack_hi(v6, v7);
  return r.s;
}

// ---------------- full gate chain (R9/R11-validated): template recursion ------------
template <int G>
__device__ __forceinline__ void apply_gates(float (&sr)[16], float (&si)[16],
                                            const float* __restrict__ w) {
  if constexpr (G < ct::GL.n) {
    constexpr int code = ct::GL.code[G];
    constexpr int kind = code & 3;
    if constexpr (kind == 3) {              // CNOT: register permutation
      constexpr int cbit = (code >> 2) & 15, tbit = (code >> 6) & 15;
      float tr[16], ti[16];
      #pragma unroll
      for (int k = 0; k < 16; k++) {
        const int src = (k & cbit) ? (k ^ tbit) : k;
        tr[k] = sr[src]; ti[k] = si[src];
      }
      #pragma unroll
      for (int k = 0; k < 16; k++) { sr[k] = tr[k]; si[k] = ti[k]; }
    } else {
      constexpr int bit  = (code >> 2) & 15;
      constexpr int widx = (code >> 6) & 31;
      float sh, ch;
      half_sincos(w[widx], sh, ch);
      float tr[16], ti[16];
      #pragma unroll
      for (int k = 0; k < 16; k++) {
        const int p = k ^ bit;
        if constexpr (kind == 0) {          // RX
          tr[k] = ch * sr[k] + sh * si[p];
          ti[k] = ch * si[k] - sh * sr[p];
        } else if constexpr (kind == 1) {   // RY
          if (k & bit) { tr[k] = ch * sr[k] + sh * sr[p]; ti[k] = ch * si[k] + sh * si[p]; }
          else         { tr[k] = ch * sr[k] - sh * sr[p]; ti[k] = ch * si[k] - sh * si[p]; }
        } else {                            // RZ
          if (k & bit) { tr[k] = ch * sr[k] - sh * si[k]; ti[k] = ch * si[k] + sh * sr[k]; }
          else         { tr[k] = ch * sr[k] + sh * si[k]; ti[k] = ch * si[k] - sh * sr[k]; }
        }
      }
      #pragma unroll
      for (int k = 0; k < 16; k++) { sr[k] = tr[k]; si[k] = ti[k]; }
    }
    apply_gates<G + 1>(sr, si, w);
  }
}

// ---------------- per-tile epilogue (R11-validated) ----------------------------------
__device__ __forceinline__ float4 tile_epi(const f32x4& ar, const f32x4& ai, int g) {
  float pk0 = ar[0]*ar[0] + ai[0]*ai[0];
  float pk1 = ar[1]*ar[1] + ai[1]*ai[1];
  float pk2 = ar[2]*ar[2] + ai[2]*ai[2];
  float pk3 = ar[3]*ar[3] + ai[3]*ai[3];
  float s  = (pk0 + pk1) + (pk2 + pk3);
  float p0 = (g & 2) ? -s : s;
  float p1 = (g & 1) ? -s : s;
  float p2 = (pk0 + pk1) - (pk2 + pk3);
  float p3 = (pk0 - pk1) + (pk2 - pk3);
  p0 += __shfl_xor(p0, 16); p0 += __shfl_xor(p0, 32);
  p1 += __shfl_xor(p1, 16); p1 += __shfl_xor(p1, 32);
  p2 += __shfl_xor(p2, 16); p2 += __shfl_xor(p2, 32);
  p3 += __shfl_xor(p3, 16); p3 += __shfl_xor(p3, 32);
  return make_float4(p0, p1, p2, p3);
}

// ---------------- single fused kernel -------------------------------------------------
// 2048 blocks x 256 thr. Wave 0 lanes 0-15: FULL gate chain (R9-validated in-kernel
// pattern), write U row-major stride-17 to LDS. All waves pre-barrier: pow2 zero-fill,
// encode 1 patch/lane, stage [chunk][patch][8] (lane-contiguous 1KB = bank-optimal).
// Post-barrier: A-frags from Uws, 4 tiles x 4 MFMA (R11-validated core), store.
__global__ __launch_bounds__(256) void qonv_fused(const float* __restrict__ img,
                                                  const float* __restrict__ wts,
                                                  float* __restrict__ out) {
  __shared__ short stage[4][4][64][8];     // 16 KB: [wave][kchunk][patch][8 bf16]
  __shared__ float2 Uws[512];              // 4 KB: U[r][c] at r*17+c (stride-17)
  const int t = threadIdx.x;
  const int lane = t & 63, w = t >> 6;
  const int c16 = lane & 15, g = lane >> 4;

  if (t < 16) {                            // ---- full chain, column t (R9 pattern)
    const int c = t;
    float sr[16], si[16];
    #pragma unroll
    for (int k = 0; k < 16; k++) { sr[k] = (k == c) ? 1.0f : 0.0f; si[k] = 0.0f; }
    apply_gates<0>(sr, si, wts);
    #pragma unroll
    for (int k = 0; k < 16; k++) Uws[k * 17 + c] = make_float2(sr[k], si[k]);
  }

  const unsigned W = blockIdx.x * 4u + (unsigned)w;
  const int b = W >> 8, jj = (W >> 1) & 127, kkb = (W & 1) * 64;
  const int kk = kkb + lane;

  // ---- zero region, pure-pow2 decode (R12, coverage-verified): A = rows 0-127 x
  //      cols 128-255 (2^14 f4/batch); B = rows 128-255 x cols 0-255 (2^15 f4/batch)
  {
    float4* o4 = (float4*)out;
    const float4 z = make_float4(0.f, 0.f, 0.f, 0.f);
    const unsigned tid = blockIdx.x * 256u + (unsigned)t;
    {
      unsigned bb = tid >> 14, rr = tid & 16383u;
      o4[((size_t)bb * 256u + (rr >> 7)) * 256u + 128u + (rr & 127u)] = z;
    }
    #pragma unroll
    for (int it = 0; it < 2; it++) {
      unsigned zi = tid + (unsigned)it * 524288u;
      unsigned bb = zi >> 15, rr = zi & 32767u;
      o4[((size_t)bb * 256u + 128u + (rr >> 8)) * 256u + (rr & 255u)] = z;
    }
  }

  // ---- encoding: one patch per lane (R11 verbatim)
  const float* row0 = img + (size_t)(b * 512 + 2 * jj) * 1536 + 6 * kk;
  const float* row1 = row0 + 1536;
  const float inv3 = 1.0f / 3.0f;
  float2 x0 = *(const float2*)(row0);
  float2 x1 = *(const float2*)(row0 + 2);
  float2 x2 = *(const float2*)(row0 + 4);
  float2 y0 = *(const float2*)(row1);
  float2 y1 = *(const float2*)(row1 + 2);
  float2 y2 = *(const float2*)(row1 + 4);
  float a0 = (x0.x + x0.y + x1.x) * inv3;
  float a1 = (x1.y + x2.x + x2.y) * inv3;
  float a2 = (y0.x + y0.y + y1.x) * inv3;
  float a3 = (y1.y + y2.x + y2.y) * inv3;
  float c0, s0, c1, s1, c2, s2, c3, s3;
  half_sincos(a0, s0, c0);
  half_sincos(a1, s1, c1);
  half_sincos(a2, s2, c2);
  half_sincos(a3, s3, c3);
  float A4[4] = {c0 * c1, c0 * s1, s0 * c1, s0 * s1};
  float B4[4] = {c2 * c3, c2 * s3, s2 * c3, s2 * s3};
  float s16[16];
  #pragma unroll
  for (int hi = 0; hi < 4; hi++)
    #pragma unroll
    for (int lo = 0; lo < 4; lo++)
      s16[hi * 4 + lo] = A4[hi] * B4[lo];

  float sh_[16], sl_[16];
  #pragma unroll
  for (int i = 0; i < 16; i++) {
    float hv = hi_part(s16[i]);
    sh_[i] = hv; sl_[i] = s16[i] - hv;
  }

  // ---- stage: chunk g' holds kk=8g'+j; per-chunk writes are lane-contiguous 1KB
  *(short8*)&stage[w][0][lane][0] = pack8(sh_[0],sh_[1],sh_[2],sh_[3],sh_[4],sh_[5],sh_[6],sh_[7]);
  *(short8*)&stage[w][1][lane][0] = pack8(sh_[8],sh_[9],sh_[10],sh_[11],sh_[12],sh_[13],sh_[14],sh_[15]);
  *(short8*)&stage[w][2][lane][0] = pack8(sl_[0],sl_[1],sl_[2],sl_[3],sl_[4],sl_[5],sl_[6],sl_[7]);
  *(short8*)&stage[w][3][lane][0] = pack8(sl_[8],sl_[9],sl_[10],sl_[11],sl_[12],sl_[13],sl_[14],sl_[15]);

  __syncthreads();                         // U ready (and staging visible)

  // ---- A-frags from U (R11 semantics): lane row=c16, kk=8g+j, i=(g&1)*8+j;
  //      hi always, lo only for kk<16 (g<2)
  float re1[8], re2[8], im1[8], im2[8];
  #pragma unroll
  for (int j = 0; j < 8; j++) {
    float2 u = Uws[c16 * 17 + (g & 1) * 8 + j];
    float reh = hi_part(u.x), imh = hi_part(u.y);
    re1[j] = reh; im1[j] = imh;
    re2[j] = (g < 2) ? (u.x - reh) : 0.f;
    im2[j] = (g < 2) ? (u.y - imh) : 0.f;
  }
  const short8 Ar1 = pack8(re1[0],re1[1],re1[2],re1[3],re1[4],re1[5],re1[6],re1[7]);
  const short8 Ar2 = pack8(re2[0],re2[1],re2[2],re2[3],re2[4],re2[5],re2[6],re2[7]);
  const short8 Ai1 = pack8(im1[0],im1[1],im1[2],im1[3],im1[4],im1[5],im1[6],im1[7]);
  const short8 Ai2 = pack8(im2[0],im2[1],im2[2],im2[3],im2[4],im2[5],im2[6],im2[7]);

  // ---- 4 tiles of 16 patches (R11-validated core)
  f32x4 zf = {0.f, 0.f, 0.f, 0.f};
  float4 res0, res1, res2, res3;
  {
    short8 B = *(const short8*)&stage[w][g][0 * 16 + c16][0];
    f32x4 ar = zf, ai = zf;
    ar = __builtin_amdgcn_mfma_f32_16x16x32_bf16(Ar1, B, ar, 0, 0, 0);
    ar = __builtin_amdgcn_mfma_f32_16x16x32_bf16(Ar2, B, ar, 0, 0, 0);
    ai = __builtin_amdgcn_mfma_f32_16x16x32_bf16(Ai1, B, ai, 0, 0, 0);
    ai = __builtin_amdgcn_mfma_f32_16x16x32_bf16(Ai2, B, ai, 0, 0, 0);
    res0 = tile_epi(ar, ai, g);
  }
  {
    short8 B = *(const short8*)&stage[w][g][1 * 16 + c16][0];
    f32x4 ar = zf, ai = zf;
    ar = __builtin_amdgcn_mfma_f32_16x16x32_bf16(Ar1, B, ar, 0, 0, 0);
    ar = __builtin_amdgcn_mfma_f32_16x16x32_bf16(Ar2, B, ar, 0, 0, 0);
    ai = __builtin_amdgcn_mfma_f32_16x16x32_bf16(Ai1, B, ai, 0, 0, 0);
    ai = __builtin_amdgcn_mfma_f32_16x16x32_bf16(Ai2, B, ai, 0, 0, 0);
    res1 = tile_epi(ar, ai, g);
  }
  {
    short8 B = *(const short8*)&stage[w][g][2 * 16 + c16][0];
    f32x4 ar = zf, ai = zf;
    ar = __builtin_amdgcn_mfma_f32_16x16x32_bf16(Ar1, B, ar, 0, 0, 0);
    ar = __builtin_amdgcn_mfma_f32_16x16x32_bf16(Ar2, B, ar, 0, 0, 0);
    ai = __builtin_amdgcn_mfma_f32_16x16x32_bf16(Ai1, B, ai, 0, 0, 0);
    ai = __builtin_amdgcn_mfma_f32_16x16x32_bf16(Ai2, B, ai, 0, 0, 0);
    res2 = tile_epi(ar, ai, g);
  }
  {
    short8 B = *(const short8*)&stage[w][g][3 * 16 + c16][0];
    f32x4 ar = zf, ai = zf;
    ar = __builtin_amdgcn_mfma_f32_16x16x32_bf16(Ar1, B, ar, 0, 0, 0);
    ar = __builtin_amdgcn_mfma_f32_16x16x32_bf16(Ar2, B, ar, 0, 0, 0);
    ai = __builtin_amdgcn_mfma_f32_16x16x32_bf16(Ai1, B, ai, 0, 0, 0);
    ai = __builtin_amdgcn_mfma_f32_16x16x32_bf16(Ai2, B, ai, 0, 0, 0);
    res3 = tile_epi(ar, ai, g);
  }

  // ---- store: lane l owns patch kkb+l -> tile g's reduced value at col c16
  float4 rA = (g & 1) ? res1 : res0;
  float4 rB = (g & 1) ? res3 : res2;
  float4 mine = (g & 2) ? rB : rA;
  ((float4*)out)[((size_t)b * 256 + jj) * 256 + kkb + lane] = mine;
}

extern "C" void kernel_launch(void* const* d_in, const int* in_sizes, int n_in,
                              void* d_out, int out_size, void* d_ws, size_t ws_size,
                              hipStream_t stream) {
  const float* img = (const float*)d_in[0];
  const float* wts = (const float*)d_in[1];
  float* out = (float*)d_out;

  qonv_fused<<<2048, 256, 0, stream>>>(img, wts, out);
}

// Round 16
// 21.233 us; speedup vs baseline: 1.1238x; 1.1238x over previous
//
#include <hip/hip_runtime.h>
#include <cstdint>
#include <cstddef>

#define MAXG 128

// ---------------- compile-time: reproduce numpy legacy RandomState(42) ----------------
namespace ct {

struct MT19937 {
  uint32_t mt[624] = {};
  int mti = 0;
  constexpr void seed(uint32_t s) {
    mt[0] = s;
    for (int i = 1; i < 624; i++)
      mt[i] = 1812433253u * (mt[i-1] ^ (mt[i-1] >> 30)) + (uint32_t)i;
    mti = 624;
  }
  constexpr uint32_t next() {
    if (mti >= 624) {
      for (int i = 0; i < 624; i++) {
        uint32_t y = (mt[i] & 0x80000000u) | (mt[(i+1) % 624] & 0x7fffffffu);
        mt[i] = mt[(i+397) % 624] ^ (y >> 1) ^ ((y & 1u) ? 2567483615u : 0u);
      }
      mti = 0;
    }
    uint32_t y = mt[mti++];
    y ^= y >> 11; y ^= (y << 7) & 2636928640u; y ^= (y << 15) & 4022730752u; y ^= y >> 18;
    return y;
  }
  constexpr double rdouble() {
    uint32_t a = next() >> 5, b = next() >> 6;
    return ((double)a * 67108864.0 + (double)b) / 9007199254740992.0;
  }
  constexpr uint32_t masked32(uint32_t rng, uint32_t mask) {
    uint32_t v = next() & mask;
    while (v > rng) v = next() & mask;
    return v;
  }
  constexpr uint32_t interval(uint32_t mx) {
    if (!mx) return 0;
    uint32_t mask = mx;
    mask |= mask >> 1; mask |= mask >> 2; mask |= mask >> 4; mask |= mask >> 8; mask |= mask >> 16;
    uint32_t v = next() & mask;
    while (v > mx) v = next() & mask;
    return v;
  }
};

struct CG { int n = 0; int code[MAXG] = {}; };

constexpr CG build_gates_ct() {
  CG gl{};
  MT19937 rng{};
  rng.seed(42);
  for (int l = 0; l < 4; l++) {
    int i = 0;
    while (i < 8) {
      if (rng.rdouble() > 0.3) {
        int g = (int)rng.masked32(2, 3);
        int w = (int)rng.masked32(3, 3);
        int widx = l * 8 + i;
        if (gl.n < MAXG) gl.code[gl.n++] = g | ((8 >> w) << 2) | (widx << 6);
        i++;
      } else {
        int perm[4] = {0, 1, 2, 3};
        for (int ii = 3; ii >= 1; ii--) {
          int j = (int)rng.interval((uint32_t)ii);
          int tmp = perm[ii]; perm[ii] = perm[j]; perm[j] = tmp;
        }
        int cw = perm[0], tw = perm[1];
        if (gl.n < MAXG) gl.code[gl.n++] = 3 | ((8 >> cw) << 2) | ((8 >> tw) << 6);
      }
    }
  }
  return gl;
}

constexpr CG GL = build_gates_ct();

} // namespace ct

typedef __attribute__((ext_vector_type(8))) short short8;   // 8 bf16 (4 VGPR) MFMA frag
typedef __attribute__((ext_vector_type(4))) float f32x4;    // 16x16 accumulator

// Native trig (validated R7/R11). Revolutions; |rev| < 0.5 for all our half-angles.
__device__ __forceinline__ void half_sincos(float a, float& s, float& c) {
  const float r = a * 0.07957747154594767f;   // a * 0.5 / (2*pi)
  s = __builtin_amdgcn_sinf(r);
  c = __builtin_amdgcn_cosf(r);
}

__device__ __forceinline__ float hi_part(float a) {
  return __uint_as_float(__float_as_uint(a) & 0xffff0000u);
}
__device__ __forceinline__ unsigned pack_hi(float a, float b) {   // low short = a's bf16
  return (__float_as_uint(a) >> 16) | (__float_as_uint(b) & 0xffff0000u);
}
__device__ __forceinline__ short8 pack8(float v0, float v1, float v2, float v3,
                                        float v4, float v5, float v6, float v7) {
  union { unsigned u[4]; short8 s; } r;
  r.u[0] = pack_hi(v0, v1); r.u[1] = pack_hi(v2, v3);
  r.u[2] = pack_hi(v4, v5); r.u[3] = pack_hi(v6, v7);
  return r.s;
}

// ---------------- full gate chain (R9/R11-validated): template recursion ------------
template <int G>
__device__ __forceinline__ void apply_gates(float (&sr)[16], float (&si)[16],
                                            const float* __restrict__ w) {
  if constexpr (G < ct::GL.n) {
    constexpr int code = ct::GL.code[G];
    constexpr int kind = code & 3;
    if constexpr (kind == 3) {              // CNOT: register permutation
      constexpr int cbit = (code >> 2) & 15, tbit = (code >> 6) & 15;
      float tr[16], ti[16];
      #pragma unroll
      for (int k = 0; k < 16; k++) {
        const int src = (k & cbit) ? (k ^ tbit) : k;
        tr[k] = sr[src]; ti[k] = si[src];
      }
      #pragma unroll
      for (int k = 0; k < 16; k++) { sr[k] = tr[k]; si[k] = ti[k]; }
    } else {
      constexpr int bit  = (code >> 2) & 15;
      constexpr int widx = (code >> 6) & 31;
      float sh, ch;
      half_sincos(w[widx], sh, ch);
      float tr[16], ti[16];
      #pragma unroll
      for (int k = 0; k < 16; k++) {
        const int p = k ^ bit;
        if constexpr (kind == 0) {          // RX
          tr[k] = ch * sr[k] + sh * si[p];
          ti[k] = ch * si[k] - sh * sr[p];
        } else if constexpr (kind == 1) {   // RY
          if (k & bit) { tr[k] = ch * sr[k] + sh * sr[p]; ti[k] = ch * si[k] + sh * si[p]; }
          else         { tr[k] = ch * sr[k] - sh * sr[p]; ti[k] = ch * si[k] - sh * si[p]; }
        } else {                            // RZ
          if (k & bit) { tr[k] = ch * sr[k] - sh * si[k]; ti[k] = ch * si[k] + sh * sr[k]; }
          else         { tr[k] = ch * sr[k] + sh * si[k]; ti[k] = ch * si[k] - sh * sr[k]; }
        }
      }
      #pragma unroll
      for (int k = 0; k < 16; k++) { sr[k] = tr[k]; si[k] = ti[k]; }
    }
    apply_gates<G + 1>(sr, si, w);
  }
}

// ---------------- kernel 1 (R11-validated VERBATIM): build U + A-fragments ----------
// K=32 semantic: kk<16 -> s_hi slot i=kk; kk>=16 -> s_lo slot i=kk-16.
// A1 = [U_hi | U_hi], A2 = [U_lo | 0]. Fragment relabel (same for A and B):
// lane l -> row=l&15, elems j=0..7 hold kk=8*(l>>4)+j.
// ws: [0]=Are1 [64]=Are2 [128]=Aim1 [192]=Aim2 (short8 idx).
__global__ __launch_bounds__(64) void build_u(const float* __restrict__ w,
                                              float* __restrict__ ws) {
  __shared__ float2 Ul[256];               // [k*16 + i] = (Re U[k][i], Im U[k][i])
  const int l = threadIdx.x;
  const int c = l & 15;
  float sr[16], si[16];
  #pragma unroll
  for (int k = 0; k < 16; k++) { sr[k] = (k == c) ? 1.0f : 0.0f; si[k] = 0.0f; }
  apply_gates<0>(sr, si, w);
  if (l < 16) {
    #pragma unroll
    for (int k = 0; k < 16; k++) Ul[k * 16 + c] = make_float2(sr[k], si[k]);
  }
  __syncthreads();

  const int row = l & 15, g = l >> 4;
  float re1[8], re2[8], im1[8], im2[8];
  #pragma unroll
  for (int j = 0; j < 8; j++) {
    const int kk = 8 * g + j;
    const int i = kk & 15;
    float2 u = Ul[row * 16 + i];
    float reh = hi_part(u.x), rel = u.x - reh;
    float imh = hi_part(u.y), iml = u.y - imh;
    re1[j] = reh;
    im1[j] = imh;
    re2[j] = (kk < 16) ? rel : 0.f;
    im2[j] = (kk < 16) ? iml : 0.f;
  }
  short8* o = (short8*)ws;
  o[l]       = pack8(re1[0],re1[1],re1[2],re1[3],re1[4],re1[5],re1[6],re1[7]);
  o[64 + l]  = pack8(re2[0],re2[1],re2[2],re2[3],re2[4],re2[5],re2[6],re2[7]);
  o[128 + l] = pack8(im1[0],im1[1],im1[2],im1[3],im1[4],im1[5],im1[6],im1[7]);
  o[192 + l] = pack8(im2[0],im2[1],im2[2],im2[3],im2[4],im2[5],im2[6],im2[7]);
}

// ---------------- per-tile epilogue (R11/R13-validated VERBATIM) ---------------------
__device__ __forceinline__ float4 tile_epi(const f32x4& ar, const f32x4& ai, int g) {
  float pk0 = ar[0]*ar[0] + ai[0]*ai[0];
  float pk1 = ar[1]*ar[1] + ai[1]*ai[1];
  float pk2 = ar[2]*ar[2] + ai[2]*ai[2];
  float pk3 = ar[3]*ar[3] + ai[3]*ai[3];
  float s  = (pk0 + pk1) + (pk2 + pk3);
  float p0 = (g & 2) ? -s : s;
  float p1 = (g & 1) ? -s : s;
  float p2 = (pk0 + pk1) - (pk2 + pk3);
  float p3 = (pk0 - pk1) + (pk2 - pk3);
  p0 += __shfl_xor(p0, 16); p0 += __shfl_xor(p0, 32);
  p1 += __shfl_xor(p1, 16); p1 += __shfl_xor(p1, 32);
  p2 += __shfl_xor(p2, 16); p2 += __shfl_xor(p2, 32);
  p3 += __shfl_xor(p3, 16); p3 += __shfl_xor(p3, 32);
  return make_float4(p0, p1, p2, p3);
}

// ---------------- kernel 2: MFMA qonv — all components replay-proven -----------------
// 2048 blocks x 256 thr. R13's core: chunked staging (lane-contiguous 1KB writes),
// MANDATORY __syncthreads (R14 hazard fix), pow2 zero-fill, 4 tiles x 4 MFMA,
// tile_epi reduce (R11/R13). A-fragment loads placed AFTER the barrier (defensive:
// ~3us into the kernel, build_u is long retired even under replay overlap).
__global__ __launch_bounds__(256) void qonv_mfma(const float* __restrict__ img,
                                                 const float* __restrict__ uws,
                                                 float* __restrict__ out) {
  __shared__ short stage[4][4][64][8];     // 16 KB: [wave][kchunk][patch][8 bf16]
  const int t = threadIdx.x;
  const int lane = t & 63, w = t >> 6;
  const int c16 = lane & 15, g = lane >> 4;

  const unsigned W = blockIdx.x * 4u + (unsigned)w;
  const int b = W >> 8, jj = (W >> 1) & 127, kkb = (W & 1) * 64;
  const int kk = kkb + lane;

  // ---- zero region, pure-pow2 decode (R13-validated)
  {
    float4* o4 = (float4*)out;
    const float4 z = make_float4(0.f, 0.f, 0.f, 0.f);
    const unsigned tid = blockIdx.x * 256u + (unsigned)t;
    {
      unsigned bb = tid >> 14, rr = tid & 16383u;
      o4[((size_t)bb * 256u + (rr >> 7)) * 256u + 128u + (rr & 127u)] = z;
    }
    #pragma unroll
    for (int it = 0; it < 2; it++) {
      unsigned zi = tid + (unsigned)it * 524288u;
      unsigned bb = zi >> 15, rr = zi & 32767u;
      o4[((size_t)bb * 256u + 128u + (rr >> 8)) * 256u + (rr & 255u)] = z;
    }
  }

  // ---- encoding: one patch per lane (R11/R13-validated verbatim)
  const float* row0 = img + (size_t)(b * 512 + 2 * jj) * 1536 + 6 * kk;
  const float* row1 = row0 + 1536;
  const float inv3 = 1.0f / 3.0f;
  float2 x0 = *(const float2*)(row0);
  float2 x1 = *(const float2*)(row0 + 2);
  float2 x2 = *(const float2*)(row0 + 4);
  float2 y0 = *(const float2*)(row1);
  float2 y1 = *(const float2*)(row1 + 2);
  float2 y2 = *(const float2*)(row1 + 4);
  float a0 = (x0.x + x0.y + x1.x) * inv3;
  float a1 = (x1.y + x2.x + x2.y) * inv3;
  float a2 = (y0.x + y0.y + y1.x) * inv3;
  float a3 = (y1.y + y2.x + y2.y) * inv3;
  float c0, s0, c1, s1, c2, s2, c3, s3;
  half_sincos(a0, s0, c0);
  half_sincos(a1, s1, c1);
  half_sincos(a2, s2, c2);
  half_sincos(a3, s3, c3);
  float A4[4] = {c0 * c1, c0 * s1, s0 * c1, s0 * s1};
  float B4[4] = {c2 * c3, c2 * s3, s2 * c3, s2 * s3};
  float s16[16];
  #pragma unroll
  for (int hi = 0; hi < 4; hi++)
    #pragma unroll
    for (int lo = 0; lo < 4; lo++)
      s16[hi * 4 + lo] = A4[hi] * B4[lo];

  float sh_[16], sl_[16];
  #pragma unroll
  for (int i = 0; i < 16; i++) {
    float hv = hi_part(s16[i]);
    sh_[i] = hv; sl_[i] = s16[i] - hv;
  }

  // ---- stage (R13-validated): chunk g' holds kk=8g'+j; lane-contiguous 1KB writes
  *(short8*)&stage[w][0][lane][0] = pack8(sh_[0],sh_[1],sh_[2],sh_[3],sh_[4],sh_[5],sh_[6],sh_[7]);
  *(short8*)&stage[w][1][lane][0] = pack8(sh_[8],sh_[9],sh_[10],sh_[11],sh_[12],sh_[13],sh_[14],sh_[15]);
  *(short8*)&stage[w][2][lane][0] = pack8(sl_[0],sl_[1],sl_[2],sl_[3],sl_[4],sl_[5],sl_[6],sl_[7]);
  *(short8*)&stage[w][3][lane][0] = pack8(sl_[8],sl_[9],sl_[10],sl_[11],sl_[12],sl_[13],sl_[14],sl_[15]);

  __syncthreads();   // MANDATORY: pins ds_write < ds_read order (R14 lesson)

  // ---- A operands (wave-uniform data, per-lane fragment) — loaded post-barrier
  const short8* A8 = (const short8*)uws;
  const short8 Ar1 = A8[lane], Ar2 = A8[64 + lane];
  const short8 Ai1 = A8[128 + lane], Ai2 = A8[192 + lane];

  // ---- 4 tiles of 16 patches (R11/R13-validated core)
  f32x4 zf = {0.f, 0.f, 0.f, 0.f};
  float4 res0, res1, res2, res3;
  {
    short8 B = *(const short8*)&stage[w][g][0 * 16 + c16][0];
    f32x4 ar = zf, ai = zf;
    ar = __builtin_amdgcn_mfma_f32_16x16x32_bf16(Ar1, B, ar, 0, 0, 0);
    ar = __builtin_amdgcn_mfma_f32_16x16x32_bf16(Ar2, B, ar, 0, 0, 0);
    ai = __builtin_amdgcn_mfma_f32_16x16x32_bf16(Ai1, B, ai, 0, 0, 0);
    ai = __builtin_amdgcn_mfma_f32_16x16x32_bf16(Ai2, B, ai, 0, 0, 0);
    res0 = tile_epi(ar, ai, g);
  }
  {
    short8 B = *(const short8*)&stage[w][g][1 * 16 + c16][0];
    f32x4 ar = zf, ai = zf;
    ar = __builtin_amdgcn_mfma_f32_16x16x32_bf16(Ar1, B, ar, 0, 0, 0);
    ar = __builtin_amdgcn_mfma_f32_16x16x32_bf16(Ar2, B, ar, 0, 0, 0);
    ai = __builtin_amdgcn_mfma_f32_16x16x32_bf16(Ai1, B, ai, 0, 0, 0);
    ai = __builtin_amdgcn_mfma_f32_16x16x32_bf16(Ai2, B, ai, 0, 0, 0);
    res1 = tile_epi(ar, ai, g);
  }
  {
    short8 B = *(const short8*)&stage[w][g][2 * 16 + c16][0];
    f32x4 ar = zf, ai = zf;
    ar = __builtin_amdgcn_mfma_f32_16x16x32_bf16(Ar1, B, ar, 0, 0, 0);
    ar = __builtin_amdgcn_mfma_f32_16x16x32_bf16(Ar2, B, ar, 0, 0, 0);
    ai = __builtin_amdgcn_mfma_f32_16x16x32_bf16(Ai1, B, ai, 0, 0, 0);
    ai = __builtin_amdgcn_mfma_f32_16x16x32_bf16(Ai2, B, ai, 0, 0, 0);
    res2 = tile_epi(ar, ai, g);
  }
  {
    short8 B = *(const short8*)&stage[w][g][3 * 16 + c16][0];
    f32x4 ar = zf, ai = zf;
    ar = __builtin_amdgcn_mfma_f32_16x16x32_bf16(Ar1, B, ar, 0, 0, 0);
    ar = __builtin_amdgcn_mfma_f32_16x16x32_bf16(Ar2, B, ar, 0, 0, 0);
    ai = __builtin_amdgcn_mfma_f32_16x16x32_bf16(Ai1, B, ai, 0, 0, 0);
    ai = __builtin_amdgcn_mfma_f32_16x16x32_bf16(Ai2, B, ai, 0, 0, 0);
    res3 = tile_epi(ar, ai, g);
  }

  // ---- store (R13-validated): lane l owns patch kkb+l -> res[g], col c16
  float4 rA = (g & 1) ? res1 : res0;
  float4 rB = (g & 1) ? res3 : res2;
  float4 mine = (g & 2) ? rB : rA;
  ((float4*)out)[((size_t)b * 256 + jj) * 256 + kkb + lane] = mine;
}

extern "C" void kernel_launch(void* const* d_in, const int* in_sizes, int n_in,
                              void* d_out, int out_size, void* d_ws, size_t ws_size,
                              hipStream_t stream) {
  const float* img = (const float*)d_in[0];
  const float* wts = (const float*)d_in[1];
  float* out = (float*)d_out;

  build_u<<<1, 64, 0, stream>>>(wts, (float*)d_ws);
  qonv_mfma<<<2048, 256, 0, stream>>>(img, (const float*)d_ws, out);
}

// Round 17
// 20.488 us; speedup vs baseline: 1.1646x; 1.0364x over previous
//
#include <hip/hip_runtime.h>
#include <cstdint>
#include <cstddef>

#define MAXG 128

// ---------------- compile-time: reproduce numpy legacy RandomState(42) ----------------
namespace ct {

struct MT19937 {
  uint32_t mt[624] = {};
  int mti = 0;
  constexpr void seed(uint32_t s) {
    mt[0] = s;
    for (int i = 1; i < 624; i++)
      mt[i] = 1812433253u * (mt[i-1] ^ (mt[i-1] >> 30)) + (uint32_t)i;
    mti = 624;
  }
  constexpr uint32_t next() {
    if (mti >= 624) {
      for (int i = 0; i < 624; i++) {
        uint32_t y = (mt[i] & 0x80000000u) | (mt[(i+1) % 624] & 0x7fffffffu);
        mt[i] = mt[(i+397) % 624] ^ (y >> 1) ^ ((y & 1u) ? 2567483615u : 0u);
      }
      mti = 0;
    }
    uint32_t y = mt[mti++];
    y ^= y >> 11; y ^= (y << 7) & 2636928640u; y ^= (y << 15) & 4022730752u; y ^= y >> 18;
    return y;
  }
  constexpr double rdouble() {
    uint32_t a = next() >> 5, b = next() >> 6;
    return ((double)a * 67108864.0 + (double)b) / 9007199254740992.0;
  }
  constexpr uint32_t masked32(uint32_t rng, uint32_t mask) {
    uint32_t v = next() & mask;
    while (v > rng) v = next() & mask;
    return v;
  }
  constexpr uint32_t interval(uint32_t mx) {
    if (!mx) return 0;
    uint32_t mask = mx;
    mask |= mask >> 1; mask |= mask >> 2; mask |= mask >> 4; mask |= mask >> 8; mask |= mask >> 16;
    uint32_t v = next() & mask;
    while (v > mx) v = next() & mask;
    return v;
  }
};

struct CG { int n = 0; int code[MAXG] = {}; };

constexpr CG build_gates_ct() {
  CG gl{};
  MT19937 rng{};
  rng.seed(42);
  for (int l = 0; l < 4; l++) {
    int i = 0;
    while (i < 8) {
      if (rng.rdouble() > 0.3) {
        int g = (int)rng.masked32(2, 3);
        int w = (int)rng.masked32(3, 3);
        int widx = l * 8 + i;
        if (gl.n < MAXG) gl.code[gl.n++] = g | ((8 >> w) << 2) | (widx << 6);
        i++;
      } else {
        int perm[4] = {0, 1, 2, 3};
        for (int ii = 3; ii >= 1; ii--) {
          int j = (int)rng.interval((uint32_t)ii);
          int tmp = perm[ii]; perm[ii] = perm[j]; perm[j] = tmp;
        }
        int cw = perm[0], tw = perm[1];
        if (gl.n < MAXG) gl.code[gl.n++] = 3 | ((8 >> cw) << 2) | ((8 >> tw) << 6);
      }
    }
  }
  return gl;
}

constexpr CG GL = build_gates_ct();

} // namespace ct

typedef __attribute__((ext_vector_type(8))) short short8;   // 8 bf16 (4 VGPR) MFMA frag
typedef __attribute__((ext_vector_type(4))) float f32x4;    // 16x16 accumulator

// Native trig (validated R7/R11). Revolutions; |rev| < 0.5 for all our half-angles.
__device__ __forceinline__ void half_sincos(float a, float& s, float& c) {
  const float r = a * 0.07957747154594767f;   // a * 0.5 / (2*pi)
  s = __builtin_amdgcn_sinf(r);
  c = __builtin_amdgcn_cosf(r);
}

__device__ __forceinline__ float hi_part(float a) {
  return __uint_as_float(__float_as_uint(a) & 0xffff0000u);
}
__device__ __forceinline__ unsigned pack_hi(float a, float b) {   // low short = a's bf16
  return (__float_as_uint(a) >> 16) | (__float_as_uint(b) & 0xffff0000u);
}
__device__ __forceinline__ short8 pack8(float v0, float v1, float v2, float v3,
                                        float v4, float v5, float v6, float v7) {
  union { unsigned u[4]; short8 s; } r;
  r.u[0] = pack_hi(v0, v1); r.u[1] = pack_hi(v2, v3);
  r.u[2] = pack_hi(v4, v5); r.u[3] = pack_hi(v6, v7);
  return r.s;
}

// ---------------- full gate chain (R9/R11-validated): template recursion ------------
template <int G>
__device__ __forceinline__ void apply_gates(float (&sr)[16], float (&si)[16],
                                            const float* __restrict__ w) {
  if constexpr (G < ct::GL.n) {
    constexpr int code = ct::GL.code[G];
    constexpr int kind = code & 3;
    if constexpr (kind == 3) {              // CNOT: register permutation
      constexpr int cbit = (code >> 2) & 15, tbit = (code >> 6) & 15;
      float tr[16], ti[16];
      #pragma unroll
      for (int k = 0; k < 16; k++) {
        const int src = (k & cbit) ? (k ^ tbit) : k;
        tr[k] = sr[src]; ti[k] = si[src];
      }
      #pragma unroll
      for (int k = 0; k < 16; k++) { sr[k] = tr[k]; si[k] = ti[k]; }
    } else {
      constexpr int bit  = (code >> 2) & 15;
      constexpr int widx = (code >> 6) & 31;
      float sh, ch;
      half_sincos(w[widx], sh, ch);
      float tr[16], ti[16];
      #pragma unroll
      for (int k = 0; k < 16; k++) {
        const int p = k ^ bit;
        if constexpr (kind == 0) {          // RX
          tr[k] = ch * sr[k] + sh * si[p];
          ti[k] = ch * si[k] - sh * sr[p];
        } else if constexpr (kind == 1) {   // RY
          if (k & bit) { tr[k] = ch * sr[k] + sh * sr[p]; ti[k] = ch * si[k] + sh * si[p]; }
          else         { tr[k] = ch * sr[k] - sh * sr[p]; ti[k] = ch * si[k] - sh * si[p]; }
        } else {                            // RZ
          if (k & bit) { tr[k] = ch * sr[k] - sh * si[k]; ti[k] = ch * si[k] + sh * sr[k]; }
          else         { tr[k] = ch * sr[k] + sh * si[k]; ti[k] = ch * si[k] - sh * sr[k]; }
        }
      }
      #pragma unroll
      for (int k = 0; k < 16; k++) { sr[k] = tr[k]; si[k] = ti[k]; }
    }
    apply_gates<G + 1>(sr, si, w);
  }
}

// ---------------- kernel 1 (R11-validated + device-scope release) -------------------
// K=32 semantic: kk<16 -> s_hi slot i=kk; kk>=16 -> s_lo slot i=kk-16.
// A1 = [U_hi | U_hi], A2 = [U_lo | 0]. Fragment relabel (same for A and B):
// lane l -> row=l&15, elems j=0..7 hold kk=8*(l>>4)+j.
// ws: [0]=Are1 [64]=Are2 [128]=Aim1 [192]=Aim2 (short8 idx).
// __threadfence() after the stores: device-scope release so qonv blocks on OTHER
// XCDs can't read stale d_ws under graph replay (R15's failure signature: poisoned
// A-frags -> zero outputs, replay-only).
__global__ __launch_bounds__(64) void build_u(const float* __restrict__ w,
                                              float* __restrict__ ws) {
  __shared__ float2 Ul[256];               // [k*16 + i] = (Re U[k][i], Im U[k][i])
  const int l = threadIdx.x;
  const int c = l & 15;
  float sr[16], si[16];
  #pragma unroll
  for (int k = 0; k < 16; k++) { sr[k] = (k == c) ? 1.0f : 0.0f; si[k] = 0.0f; }
  apply_gates<0>(sr, si, w);
  if (l < 16) {
    #pragma unroll
    for (int k = 0; k < 16; k++) Ul[k * 16 + c] = make_float2(sr[k], si[k]);
  }
  __syncthreads();

  const int row = l & 15, g = l >> 4;
  float re1[8], re2[8], im1[8], im2[8];
  #pragma unroll
  for (int j = 0; j < 8; j++) {
    const int kk = 8 * g + j;
    const int i = kk & 15;
    float2 u = Ul[row * 16 + i];
    float reh = hi_part(u.x), rel = u.x - reh;
    float imh = hi_part(u.y), iml = u.y - imh;
    re1[j] = reh;
    im1[j] = imh;
    re2[j] = (kk < 16) ? rel : 0.f;
    im2[j] = (kk < 16) ? iml : 0.f;
  }
  short8* o = (short8*)ws;
  o[l]       = pack8(re1[0],re1[1],re1[2],re1[3],re1[4],re1[5],re1[6],re1[7]);
  o[64 + l]  = pack8(re2[0],re2[1],re2[2],re2[3],re2[4],re2[5],re2[6],re2[7]);
  o[128 + l] = pack8(im1[0],im1[1],im1[2],im1[3],im1[4],im1[5],im1[6],im1[7]);
  o[192 + l] = pack8(im2[0],im2[1],im2[2],im2[3],im2[4],im2[5],im2[6],im2[7]);
  __threadfence();                         // device-scope release of d_ws
}

// ---------------- per-tile PARTIAL (R15 first-validation-proven) ---------------------
__device__ __forceinline__ float4 tile_part(const f32x4& ar, const f32x4& ai, int g) {
  float pk0 = ar[0]*ar[0] + ai[0]*ai[0];
  float pk1 = ar[1]*ar[1] + ai[1]*ai[1];
  float pk2 = ar[2]*ar[2] + ai[2]*ai[2];
  float pk3 = ar[3]*ar[3] + ai[3]*ai[3];
  float s  = (pk0 + pk1) + (pk2 + pk3);
  float p0 = (g & 2) ? -s : s;
  float p1 = (g & 1) ? -s : s;
  float p2 = (pk0 + pk1) - (pk2 + pk3);
  float p3 = (pk0 - pk1) + (pk2 - pk3);
  return make_float4(p0, p1, p2, p3);
}

__device__ __forceinline__ float4 f4add_shfl(const float4& keep, const float4& send,
                                             int mask) {
  return make_float4(keep.x + __shfl_xor(send.x, mask),
                     keep.y + __shfl_xor(send.y, mask),
                     keep.z + __shfl_xor(send.z, mask),
                     keep.w + __shfl_xor(send.w, mask));
}

// ---------------- kernel 2: MFMA qonv (R16 skeleton + butterfly epilogue) ------------
// 2048 blocks x 256 thr. Chunked staging (lane-contiguous 1KB writes), MANDATORY
// __syncthreads (R14 lesson), pow2 zero-fill, A-frag loads POST-barrier (R16 lesson:
// masks the d_ws replay race; now also fenced at the producer). Butterfly
// reduce-scatter: 12 shfl instead of 32 (algebra silicon-proven by R15's first pass).
__global__ __launch_bounds__(256) void qonv_mfma(const float* __restrict__ img,
                                                 const float* __restrict__ uws,
                                                 float* __restrict__ out) {
  __shared__ short stage[4][4][64][8];     // 16 KB: [wave][kchunk][patch][8 bf16]
  const int t = threadIdx.x;
  const int lane = t & 63, w = t >> 6;
  const int c16 = lane & 15, g = lane >> 4;

  const unsigned W = blockIdx.x * 4u + (unsigned)w;
  const int b = W >> 8, jj = (W >> 1) & 127, kkb = (W & 1) * 64;
  const int kk = kkb + lane;

  // ---- zero region, pure-pow2 decode (R13/R16-validated)
  {
    float4* o4 = (float4*)out;
    const float4 z = make_float4(0.f, 0.f, 0.f, 0.f);
    const unsigned tid = blockIdx.x * 256u + (unsigned)t;
    {
      unsigned bb = tid >> 14, rr = tid & 16383u;
      o4[((size_t)bb * 256u + (rr >> 7)) * 256u + 128u + (rr & 127u)] = z;
    }
    #pragma unroll
    for (int it = 0; it < 2; it++) {
      unsigned zi = tid + (unsigned)it * 524288u;
      unsigned bb = zi >> 15, rr = zi & 32767u;
      o4[((size_t)bb * 256u + 128u + (rr >> 8)) * 256u + (rr & 255u)] = z;
    }
  }

  // ---- encoding: one patch per lane (R11/R13/R16-validated verbatim)
  const float* row0 = img + (size_t)(b * 512 + 2 * jj) * 1536 + 6 * kk;
  const float* row1 = row0 + 1536;
  const float inv3 = 1.0f / 3.0f;
  float2 x0 = *(const float2*)(row0);
  float2 x1 = *(const float2*)(row0 + 2);
  float2 x2 = *(const float2*)(row0 + 4);
  float2 y0 = *(const float2*)(row1);
  float2 y1 = *(const float2*)(row1 + 2);
  float2 y2 = *(const float2*)(row1 + 4);
  float a0 = (x0.x + x0.y + x1.x) * inv3;
  float a1 = (x1.y + x2.x + x2.y) * inv3;
  float a2 = (y0.x + y0.y + y1.x) * inv3;
  float a3 = (y1.y + y2.x + y2.y) * inv3;
  float c0, s0, c1, s1, c2, s2, c3, s3;
  half_sincos(a0, s0, c0);
  half_sincos(a1, s1, c1);
  half_sincos(a2, s2, c2);
  half_sincos(a3, s3, c3);
  float A4[4] = {c0 * c1, c0 * s1, s0 * c1, s0 * s1};
  float B4[4] = {c2 * c3, c2 * s3, s2 * c3, s2 * s3};
  float s16[16];
  #pragma unroll
  for (int hi = 0; hi < 4; hi++)
    #pragma unroll
    for (int lo = 0; lo < 4; lo++)
      s16[hi * 4 + lo] = A4[hi] * B4[lo];

  float sh_[16], sl_[16];
  #pragma unroll
  for (int i = 0; i < 16; i++) {
    float hv = hi_part(s16[i]);
    sh_[i] = hv; sl_[i] = s16[i] - hv;
  }

  // ---- stage (R13/R16-validated): chunk g' holds kk=8g'+j; lane-contiguous 1KB
  *(short8*)&stage[w][0][lane][0] = pack8(sh_[0],sh_[1],sh_[2],sh_[3],sh_[4],sh_[5],sh_[6],sh_[7]);
  *(short8*)&stage[w][1][lane][0] = pack8(sh_[8],sh_[9],sh_[10],sh_[11],sh_[12],sh_[13],sh_[14],sh_[15]);
  *(short8*)&stage[w][2][lane][0] = pack8(sl_[0],sl_[1],sl_[2],sl_[3],sl_[4],sl_[5],sl_[6],sl_[7]);
  *(short8*)&stage[w][3][lane][0] = pack8(sl_[8],sl_[9],sl_[10],sl_[11],sl_[12],sl_[13],sl_[14],sl_[15]);

  __syncthreads();   // MANDATORY: pins ds_write < ds_read order (R14 lesson)

  // ---- A operands loaded POST-barrier (R16-validated; replay-race mitigation)
  const short8* A8 = (const short8*)uws;
  const short8 Ar1 = A8[lane], Ar2 = A8[64 + lane];
  const short8 Ai1 = A8[128 + lane], Ai2 = A8[192 + lane];

  // ---- 4 tiles of 16 patches (R11/R13/R16-validated core), partials only
  f32x4 zf = {0.f, 0.f, 0.f, 0.f};
  float4 P0, P1, P2, P3;
  {
    short8 B = *(const short8*)&stage[w][g][0 * 16 + c16][0];
    f32x4 ar = zf, ai = zf;
    ar = __builtin_amdgcn_mfma_f32_16x16x32_bf16(Ar1, B, ar, 0, 0, 0);
    ar = __builtin_amdgcn_mfma_f32_16x16x32_bf16(Ar2, B, ar, 0, 0, 0);
    ai = __builtin_amdgcn_mfma_f32_16x16x32_bf16(Ai1, B, ai, 0, 0, 0);
    ai = __builtin_amdgcn_mfma_f32_16x16x32_bf16(Ai2, B, ai, 0, 0, 0);
    P0 = tile_part(ar, ai, g);
  }
  {
    short8 B = *(const short8*)&stage[w][g][1 * 16 + c16][0];
    f32x4 ar = zf, ai = zf;
    ar = __builtin_amdgcn_mfma_f32_16x16x32_bf16(Ar1, B, ar, 0, 0, 0);
    ar = __builtin_amdgcn_mfma_f32_16x16x32_bf16(Ar2, B, ar, 0, 0, 0);
    ai = __builtin_amdgcn_mfma_f32_16x16x32_bf16(Ai1, B, ai, 0, 0, 0);
    ai = __builtin_amdgcn_mfma_f32_16x16x32_bf16(Ai2, B, ai, 0, 0, 0);
    P1 = tile_part(ar, ai, g);
  }
  {
    short8 B = *(const short8*)&stage[w][g][2 * 16 + c16][0];
    f32x4 ar = zf, ai = zf;
    ar = __builtin_amdgcn_mfma_f32_16x16x32_bf16(Ar1, B, ar, 0, 0, 0);
    ar = __builtin_amdgcn_mfma_f32_16x16x32_bf16(Ar2, B, ar, 0, 0, 0);
    ai = __builtin_amdgcn_mfma_f32_16x16x32_bf16(Ai1, B, ai, 0, 0, 0);
    ai = __builtin_amdgcn_mfma_f32_16x16x32_bf16(Ai2, B, ai, 0, 0, 0);
    P2 = tile_part(ar, ai, g);
  }
  {
    short8 B = *(const short8*)&stage[w][g][3 * 16 + c16][0];
    f32x4 ar = zf, ai = zf;
    ar = __builtin_amdgcn_mfma_f32_16x16x32_bf16(Ar1, B, ar, 0, 0, 0);
    ar = __builtin_amdgcn_mfma_f32_16x16x32_bf16(Ar2, B, ar, 0, 0, 0);
    ai = __builtin_amdgcn_mfma_f32_16x16x32_bf16(Ai1, B, ai, 0, 0, 0);
    ai = __builtin_amdgcn_mfma_f32_16x16x32_bf16(Ai2, B, ai, 0, 0, 0);
    P3 = tile_part(ar, ai, g);
  }

  // ---- butterfly reduce-scatter (algebra proven on HW, R15 first pass):
  // step 1 (xor16) keeps tiles with parity g&1; step 2 (xor32) keeps half g>>1;
  // lane ends with exactly tile g = its own patch kkb+lane.
  const bool g1 = (g & 1) != 0, g2 = (g & 2) != 0;
  float4 k0 = g1 ? P1 : P0, s0_ = g1 ? P0 : P1;
  float4 k1 = g1 ? P3 : P2, s1_ = g1 ? P2 : P3;
  float4 Q0 = f4add_shfl(k0, s0_, 16);
  float4 Q1 = f4add_shfl(k1, s1_, 16);
  float4 kq = g2 ? Q1 : Q0, sq = g2 ? Q0 : Q1;
  float4 R = f4add_shfl(kq, sq, 32);

  // ---- store: lane l owns patch kkb+l (= tile g, col c16)
  ((float4*)out)[((size_t)b * 256 + jj) * 256 + kkb + lane] = R;
}

extern "C" void kernel_launch(void* const* d_in, const int* in_sizes, int n_in,
                              void* d_out, int out_size, void* d_ws, size_t ws_size,
                              hipStream_t stream) {
  const float* img = (const float*)d_in[0];
  const float* wts = (const float*)d_in[1];
  float* out = (float*)d_out;

  build_u<<<1, 64, 0, stream>>>(wts, (float*)d_ws);
  qonv_mfma<<<2048, 256, 0, stream>>>(img, (const float*)d_ws, out);
}